// Round 13
// baseline (251.413 us; speedup 1.0000x reference)
//
#include <hip/hip_runtime.h>
#include <math.h>

// Kobayashi dendrite single timestep, B=4, H=W=2048, fp32, periodic BCs.
// Round 18: float4 (16B/lane) quad-streaming. Evidence r6..r14: FIVE distinct
// structures (3-phase LDS x3, LDS-tempr, barrier-free streaming) all pinned
// at 84-87us / ~3.2 TB/s on ~compulsory traffic, VALUBusy varying 45-65%.
// Only invariant = HBM rate. 3.2 = exactly half the 6.3 TB/s float4-copy
// ceiling; every kernel so far used 4-8B accesses. Test access width:
// lane owns 4 consecutive cols (float4 loads/stores), in-quad neighbors from
// registers, only quad edges shuffle. Wave = 256 cols x SH=16 rows.
// If flat at ~90us -> 3.2 TB/s is the pattern ceiling -> declare roofline.

#define Bz 4
#define Hd 2048
#define Wd 2048
#define SH 16          // rows per wave
#define WPB 4          // waves per 256-thread block

#define INVD2   1111.11111111111f      // 1/0.03^2
#define K1c     277.777777777778f      // 1/(2*0.03)^2 (raw-diff fold)
#define DT_TAU  0.333333333333333f     // 1e-4 / 3e-4
#define DTc     1e-4f
#define KAPPAc  1.8f
#define EPSB    0.01f
#define DELTAc  0.02f
#define ANISOc  6.0f
#define A_PI    0.2864788975654116f    // 0.9/pi
#define GAMMAc  10.0f
#define TEQc    1.0f
#define C6T0    0.3623577544766736f    // cos(1.2)
#define S6T0    0.9320390859672263f    // sin(1.2)
#define PI_2    1.5707963267948966f

// prod from RAW central diffs (1/(2d) cancels in theta; folded into K1c).
__device__ __forceinline__ void prodc(float dx, float dy,
                                      float& p1, float& p2, float& e2)
{
    float dx2 = dx * dx;
    float r2  = fmaf(dy, dy, dx2);
    float cn  = fmaf(-dy, dy, dx2);
    float irr = __builtin_amdgcn_rcpf(fmaxf(r2, 1e-20f));
    float c2  = cn * irr;
    float s2  = 2.0f * dx * dy * irr;
    float c6  = c2 * fmaf(4.0f, c2 * c2, -3.0f);
    float s6  = s2 * fmaf(-4.0f, s2 * s2, 3.0f);
    float cosA = fmaf(c6, C6T0, s6 * S6T0);
    float sinA = fmaf(s6, C6T0, -c6 * S6T0);
    float eps  = fmaf(EPSB * DELTAc, cosA, EPSB);
    float ee   = eps * (-EPSB * ANISOc * DELTAc) * sinA;
    p1 = ee * dx;
    p2 = -ee * dy;
    e2 = eps * eps;
}

// atan(g), g in (0,10]; deg-7 odd minimax on [0,1] + rcp fold. |err|<=6.3e-4.
__device__ __forceinline__ float atan_fast(float g) {
    float r  = __builtin_amdgcn_rcpf(g);
    float a  = fminf(g, r);
    float a2 = a * a;
    float p  = a * fmaf(a2, fmaf(a2, 0.079331f, -0.288679f), 0.995354f);
    return (g <= 1.0f) ? p : PI_2 - p;
}

// one output cell: pm/pc/pp = phi rows y-1/y/y+1; pl/pr = phi x-neighbors;
// p1p_/p1m_ = p1 rows y+1/y-1; p2l_/p2r_ = p2 x-neighbors; tm/tc/tn/tl/tr
// = tempr stencil.
__device__ __forceinline__ void cellout(
    float pm, float pc, float pp, float pl, float pr,
    float p1p_, float p1m_, float p2l_, float p2r_, float e2_,
    float tm_, float tc_, float tn_, float tl_, float tr_,
    float& op, float& ot)
{
    float t12  = (p1p_ - p1m_ + p2r_ - p2l_) * K1c;
    float lapp = (pl + pr + pm + pp - 4.0f * pc) * INVD2;
    float lapt = (tl_ + tr_ + tm_ + tn_ - 4.0f * tc_) * INVD2;
    float mval = A_PI * atan_fast(GAMMAc * (TEQc - tc_));
    float dphi = DT_TAU * (t12 + e2_ * lapp
                   + pc * (1.0f - pc) * (pc - 0.5f + mval));
    op = pc + dphi;
    ot = fmaf(KAPPAc, dphi, fmaf(DTc, lapt, tc_));
}

__global__ __launch_bounds__(256, 4) void dendrite_step(
    const float* __restrict__ phi, const float* __restrict__ tempr,
    float* __restrict__ out_phi, float* __restrict__ out_tempr)
{
    const int tid  = threadIdx.x;
    const int lane = tid & 63;
    const int wv   = tid >> 6;
    const int x0   = blockIdx.x * 256;
    const int y0   = blockIdx.y * (WPB * SH) + wv * SH;
    const int base = blockIdx.z * (Hd * Wd);
    const int gx   = x0 + 4 * lane;     // first col of this lane's quad

    const bool eL = (lane == 0);
    const bool eR = (lane == 63);
    const bool eE = eL || eR;
    // phi halo float2: (x0-2,x0-1) left / (x0+256,x0+257) right. 8B aligned.
    const int hxc = eL ? ((x0 - 2) & (Wd - 1)) : ((x0 + 256) & (Wd - 1));
    // tempr halo col: x0-1 / x0+256
    const int thx = eL ? ((x0 - 1) & (Wd - 1)) : ((x0 + 256) & (Wd - 1));

    auto prow = [&](const float* a, int r) {
        return a + base + ((y0 + r) & (Hd - 1)) * Wd;
    };

    // ---- prologue: rolling windows (rows rel. to first output row y0) ----
    float4 P0 = *(const float4*)(prow(phi, -2) + gx);
    float4 P1 = *(const float4*)(prow(phi, -1) + gx);
    float4 P2 = *(const float4*)(prow(phi,  0) + gx);
    float4 P3 = *(const float4*)(prow(phi,  1) + gx);
    float4 P4 = *(const float4*)(prow(phi,  2) + gx);
    float4 T0 = *(const float4*)(prow(tempr, -1) + gx);
    float4 T1 = *(const float4*)(prow(tempr,  0) + gx);
    float4 T2 = *(const float4*)(prow(tempr,  1) + gx);

    float2 Hmm = make_float2(0.f, 0.f), Hm = Hmm, Hc = Hmm, Hp = Hmm;
    float tH_c = 0.0f;
    if (eE) {
        Hmm = *(const float2*)(prow(phi, -1) + hxc);
        Hm  = *(const float2*)(prow(phi,  0) + hxc);
        Hc  = *(const float2*)(prow(phi,  1) + hxc);
        Hp  = *(const float2*)(prow(phi,  2) + hxc);
        tH_c = prow(tempr, 0)[thx];
    }

    // quad-edge scalars for rows y0-1 and y0
    float plm = __shfl_up(P1.w, 1), prm = __shfl_down(P1.x, 1);
    if (eL) plm = Hmm.y;
    if (eR) prm = Hmm.x;
    float plc = __shfl_up(P2.w, 1), prc = __shfl_down(P2.x, 1);
    if (eL) plc = Hm.y;
    if (eR) prc = Hm.x;
    float tlc = __shfl_up(T1.w, 1), trc = __shfl_down(T1.x, 1);
    if (eL) tlc = tH_c;
    if (eR) trc = tH_c;

    // p1 at row y0-1 (dy = P2 - P0)
    float4 p1m, p1c, p2c, e2c;
    {
        float d0, d1;
        prodc(P1.y - plm,  P2.x - P0.x, p1m.x, d0, d1);
        prodc(P1.z - P1.x, P2.y - P0.y, p1m.y, d0, d1);
        prodc(P1.w - P1.y, P2.z - P0.z, p1m.z, d0, d1);
        prodc(prm  - P1.z, P2.w - P0.w, p1m.w, d0, d1);
    }
    // full prodc at row y0 (dy = P3 - P1)
    prodc(P2.y - plc,  P3.x - P1.x, p1c.x, p2c.x, e2c.x);
    prodc(P2.z - P2.x, P3.y - P1.y, p1c.y, p2c.y, e2c.y);
    prodc(P2.w - P2.y, P3.z - P1.z, p1c.z, p2c.z, e2c.z);
    prodc(prc  - P2.z, P3.w - P1.w, p1c.w, p2c.w, e2c.w);

    float p2h_c = 0.0f;
    if (eE) {
        float dxh = eL ? (P2.x - Hm.x) : (Hm.y - P2.w);
        float mp  = eL ? Hc.y  : Hc.x;
        float mmv = eL ? Hmm.y : Hmm.x;
        float a, c_;
        prodc(dxh, mp - mmv, a, p2h_c, c_);
        (void)a; (void)c_;
    }

    const int omask = Hd * Wd - 1;
    int oP  = ((y0 + 3) & (Hd - 1)) * Wd;    // phi row y+3
    int oT  = ((y0 + 2) & (Hd - 1)) * Wd;    // tempr row y+2
    int oTH = ((y0 + 1) & (Hd - 1)) * Wd;    // tempr halo row y+1
    int gout = base + y0 * Wd + gx;

    #pragma unroll 4
    for (int k = 0; k < SH; ++k) {
        // prefetch next rows (skip on last iteration - values never used)
        float4 Pn = make_float4(0.f, 0.f, 0.f, 0.f);
        float4 Tn = Pn;
        float2 Hn = make_float2(0.f, 0.f);
        float tHn = 0.0f;
        if (k < SH - 1) {
            Pn = *(const float4*)(phi + base + oP + gx);
            Tn = *(const float4*)(tempr + base + oT + gx);
            if (eE) {
                Hn  = *(const float2*)(phi + base + oP + hxc);
                tHn = tempr[base + oTH + thx];
            }
        } else if (eE) {
            tHn = tempr[base + oTH + thx];   // still needed for row y+1 lap
        }

        // quad-edge scalars for row y+1
        float pl1 = __shfl_up(P3.w, 1), pr1 = __shfl_down(P3.x, 1);
        if (eL) pl1 = Hc.y;
        if (eR) pr1 = Hc.x;

        // prodc at row y+1 (dy = P4 - P2)
        float4 p1p, p2n, e2n;
        prodc(P3.y - pl1,  P4.x - P2.x, p1p.x, p2n.x, e2n.x);
        prodc(P3.z - P3.x, P4.y - P2.y, p1p.y, p2n.y, e2n.y);
        prodc(P3.w - P3.y, P4.z - P2.z, p1p.z, p2n.z, e2n.z);
        prodc(pr1  - P3.z, P4.w - P2.w, p1p.w, p2n.w, e2n.w);

        // halo prodc at row y+1 (wave-edge cols x0-1 / x0+256)
        float p2h_n = 0.0f;
        if (eE) {
            float dxh = eL ? (P3.x - Hc.x) : (Hc.y - P3.w);
            float mp  = eL ? Hp.y : Hp.x;
            float mmv = eL ? Hm.y : Hm.x;
            float a, c_;
            prodc(dxh, mp - mmv, a, p2h_n, c_);
            (void)a; (void)c_;
        }

        // tempr quad-edge for row y+1 (used next iteration)
        float tl_n = __shfl_up(T2.w, 1), tr_n = __shfl_down(T2.x, 1);
        if (eL) tl_n = tHn;
        if (eR) tr_n = tHn;

        // p2 quad-edge at row y
        float p2l = __shfl_up(p2c.w, 1), p2r = __shfl_down(p2c.x, 1);
        if (eL) p2l = p2h_c;
        if (eR) p2r = p2h_c;

        // assemble 4 output cells for row y
        float4 OPv, OTv;
        cellout(P1.x, P2.x, P3.x, plc,  P2.y, p1p.x, p1m.x, p2l,   p2c.y,
                e2c.x, T0.x, T1.x, T2.x, tlc,  T1.y, OPv.x, OTv.x);
        cellout(P1.y, P2.y, P3.y, P2.x, P2.z, p1p.y, p1m.y, p2c.x, p2c.z,
                e2c.y, T0.y, T1.y, T2.y, T1.x, T1.z, OPv.y, OTv.y);
        cellout(P1.z, P2.z, P3.z, P2.y, P2.w, p1p.z, p1m.z, p2c.y, p2c.w,
                e2c.z, T0.z, T1.z, T2.z, T1.y, T1.w, OPv.z, OTv.z);
        cellout(P1.w, P2.w, P3.w, P2.z, prc,  p1p.w, p1m.w, p2c.z, p2r,
                e2c.w, T0.w, T1.w, T2.w, T1.z, trc,  OPv.w, OTv.w);

        *(float4*)(out_phi + gout)   = OPv;
        *(float4*)(out_tempr + gout) = OTv;

        // roll windows
        P0 = P1; P1 = P2; P2 = P3; P3 = P4; P4 = Pn;
        plc = pl1; prc = pr1;
        p1m = p1c; p1c = p1p;
        p2c = p2n; e2c = e2n; p2h_c = p2h_n;
        T0 = T1; T1 = T2; T2 = Tn;
        tlc = tl_n; trc = tr_n;
        Hm = Hc; Hc = Hp; Hp = Hn;

        oP  = (oP  + Wd) & omask;
        oT  = (oT  + Wd) & omask;
        oTH = (oTH + Wd) & omask;
        gout += Wd;
    }
}

extern "C" void kernel_launch(void* const* d_in, const int* in_sizes, int n_in,
                              void* d_out, int out_size, void* d_ws, size_t ws_size,
                              hipStream_t stream) {
    const float* phi = (const float*)d_in[0];
    const float* tempr = (const float*)d_in[1];
    float* out_phi = (float*)d_out;
    float* out_tempr = out_phi + (size_t)Bz * Hd * Wd;

    dim3 grid(Wd / 256, Hd / (WPB * SH), Bz);
    dendrite_step<<<grid, 256, 0, stream>>>(phi, tempr, out_phi, out_tempr);
}

// Round 15
// 247.995 us; speedup vs baseline: 1.0138x; 1.0138x over previous
//
#include <hip/hip_runtime.h>
#include <math.h>

// Kobayashi dendrite single timestep, B=4, H=W=2048, fp32, periodic BCs.
// Round 19: r12 wave-streaming kernel + NONTEMPORAL output stores (only
// change). Evidence r6..r18: six structures pinned at 84-92us / ~3.2 TB/s
// regardless of occupancy (39-77%) or VALUBusy (28-65%) -> memory system
// saturates, not request-starved. r18 clues: WRITE inflated 23% over
// compulsory, FETCH < compulsory -> ~268MB working set thrashes the 256MB
// L3; write-allocated output lines evict input lines. NT stores bypass
// cache allocation: inputs become L3-resident, writes stream to HBM.
// Predict dur 87 -> 58-72us, FETCH << 134MB, WRITE exactly 134MB.
// Round 20: byte-identical resubmission (r19 bench died at GPU acquisition;
// the NT-store experiment has never been measured).

#define Bz 4
#define Hd 2048
#define Wd 2048
#define SH 32          // rows per wave
#define WPB 4          // waves per 256-thread block

#define INVD2   1111.11111111111f      // 1/0.03^2
#define K1c     277.777777777778f      // 1/(2*0.03)^2 (raw-diff fold)
#define DT_TAU  0.333333333333333f     // 1e-4 / 3e-4
#define DTc     1e-4f
#define KAPPAc  1.8f
#define EPSB    0.01f
#define DELTAc  0.02f
#define ANISOc  6.0f
#define A_PI    0.2864788975654116f    // 0.9/pi
#define GAMMAc  10.0f
#define TEQc    1.0f
#define C6T0    0.3623577544766736f    // cos(1.2)
#define S6T0    0.9320390859672263f    // sin(1.2)
#define PI_2    1.5707963267948966f

// prod from RAW central diffs (1/(2d) cancels in theta; folded into K1c).
__device__ __forceinline__ void prodc(float dx, float dy,
                                      float& p1, float& p2, float& e2)
{
    float dx2 = dx * dx;
    float r2  = fmaf(dy, dy, dx2);
    float cn  = fmaf(-dy, dy, dx2);
    float irr = __builtin_amdgcn_rcpf(fmaxf(r2, 1e-20f));
    float c2  = cn * irr;
    float s2  = 2.0f * dx * dy * irr;
    float c6  = c2 * fmaf(4.0f, c2 * c2, -3.0f);
    float s6  = s2 * fmaf(-4.0f, s2 * s2, 3.0f);
    float cosA = fmaf(c6, C6T0, s6 * S6T0);
    float sinA = fmaf(s6, C6T0, -c6 * S6T0);
    float eps  = fmaf(EPSB * DELTAc, cosA, EPSB);
    float ee   = eps * (-EPSB * ANISOc * DELTAc) * sinA;
    p1 = ee * dx;
    p2 = -ee * dy;
    e2 = eps * eps;
}

// atan(g), g in (0,10]; deg-7 odd minimax on [0,1] + rcp fold. |err|<=6.3e-4.
__device__ __forceinline__ float atan_fast(float g) {
    float r  = __builtin_amdgcn_rcpf(g);
    float a  = fminf(g, r);
    float a2 = a * a;
    float p  = a * fmaf(a2, fmaf(a2, 0.079331f, -0.288679f), 0.995354f);
    return (g <= 1.0f) ? p : PI_2 - p;
}

__global__ __launch_bounds__(256) void dendrite_step(
    const float* __restrict__ phi, const float* __restrict__ tempr,
    float* __restrict__ out_phi, float* __restrict__ out_tempr)
{
    const int tid  = threadIdx.x;
    const int lane = tid & 63;
    const int wv   = tid >> 6;
    const int x0   = blockIdx.x * 64;
    const int y0   = blockIdx.y * (WPB * SH) + wv * SH;
    const int base = blockIdx.z * (Hd * Wd);
    const int gx   = x0 + lane;

    const bool eL = (lane == 0);
    const bool eR = (lane == 63);
    const bool eE = eL || eR;
    // phi halo float2 start col: (x0-2,x0-1) for eL, (x0+64,x0+65) for eR.
    const int hxc = eL ? ((x0 - 2) & (Wd - 1)) : ((x0 + 64) & (Wd - 1));
    // tempr halo col: x0-1 (eL) / x0+64 (eR)
    const int thx = eL ? ((x0 - 1) & (Wd - 1)) : ((x0 + 64) & (Wd - 1));

    auto prow = [&](const float* a, int r) {
        return a + base + ((y0 + r) & (Hd - 1)) * Wd;
    };

    // ---- prologue: fill rolling windows ----
    float pc_m2 = prow(phi, -2)[gx];
    float pc_m1 = prow(phi, -1)[gx];
    float pc_0  = prow(phi,  0)[gx];
    float pc_p1 = prow(phi,  1)[gx];
    float pc_p2 = prow(phi,  2)[gx];
    float tm = prow(tempr, -1)[gx];
    float tc = prow(tempr,  0)[gx];
    float tn = prow(tempr,  1)[gx];

    float2 Hmm = make_float2(0.f, 0.f), Hm = Hmm, Hc = Hmm, Hp = Hmm;
    float tH_c = 0.0f;
    if (eE) {
        Hmm = *(const float2*)(prow(phi, -1) + hxc);
        Hm  = *(const float2*)(prow(phi,  0) + hxc);
        Hc  = *(const float2*)(prow(phi,  1) + hxc);
        Hp  = *(const float2*)(prow(phi,  2) + hxc);
        tH_c = prow(tempr, 0)[thx];
    }

    // LR shuffles for rows y0-1 (prodc) and y0 (prodc + lap)
    float plm = __shfl_up(pc_m1, 1), prm = __shfl_down(pc_m1, 1);
    float plc = __shfl_up(pc_0, 1),  prc = __shfl_down(pc_0, 1);
    if (eL) { plm = Hmm.y; plc = Hm.y; }
    if (eR) { prm = Hmm.x; prc = Hm.x; }
    float tlc = __shfl_up(tc, 1), trc = __shfl_down(tc, 1);
    if (eL) tlc = tH_c;
    if (eR) trc = tH_c;

    float p1m, p1c, p2c, e2c, du0, du1;
    prodc(prm - plm, pc_0 - pc_m2, p1m, du0, du1);      // row y0-1 (p1 only)
    prodc(prc - plc, pc_p1 - pc_m1, p1c, p2c, e2c);     // row y0

    float p2h_c = 0.0f;
    if (eE) {
        float dxh = eL ? (pc_0 - Hm.x) : (Hm.y - pc_0);
        float mp  = eL ? Hc.y  : Hc.x;    // mid col, row y0+1
        float mmv = eL ? Hmm.y : Hmm.x;   // mid col, row y0-1
        float a, c_;
        prodc(dxh, mp - mmv, a, p2h_c, c_);
        (void)a; (void)c_;
    }

    // rolling wrapped row offsets for in-loop loads
    const int omask = Hd * Wd - 1;
    int oP  = ((y0 + 3) & (Hd - 1)) * Wd;    // phi row y+3
    int oT  = ((y0 + 2) & (Hd - 1)) * Wd;    // tempr row y+2
    int oTH = ((y0 + 1) & (Hd - 1)) * Wd;    // tempr halo row y+1
    int gout = base + y0 * Wd + gx;

    #pragma unroll 4
    for (int k = 0; k < SH; ++k) {
        // issue next-row streaming loads (consumed next step / end of step)
        float ph_new = phi[base + oP + gx];
        float t_new  = tempr[base + oT + gx];
        float2 H_new = make_float2(0.f, 0.f);
        float tH_n = 0.0f;
        if (eE) {
            H_new = *(const float2*)(phi + base + oP + hxc);
            tH_n  = tempr[base + oTH + thx];
        }

        // prodc at row y+1 (needs LR of pc_p1, dy = pc_p2 - pc_0)
        float pl1 = __shfl_up(pc_p1, 1), pr1 = __shfl_down(pc_p1, 1);
        if (eL) pl1 = Hc.y;
        if (eR) pr1 = Hc.x;
        float p1p, p2n, e2n;
        prodc(pr1 - pl1, pc_p2 - pc_0, p1p, p2n, e2n);

        // halo prodc at row y+1 (strip-edge cols x0-1 / x0+64)
        float p2h_n = 0.0f;
        if (eE) {
            float dxh = eL ? (pc_p1 - Hc.x) : (Hc.y - pc_p1);
            float mp  = eL ? Hp.y : Hp.x;   // row y+2
            float mmv = eL ? Hm.y : Hm.x;   // row y
            float a, c_;
            prodc(dxh, mp - mmv, a, p2h_n, c_);
            (void)a; (void)c_;
        }

        // tempr LR for row y+1 (used next step)
        float tl_n = __shfl_up(tn, 1), tr_n = __shfl_down(tn, 1);
        if (eL) tl_n = tH_n;
        if (eR) tr_n = tH_n;

        // p2 x-neighbors at row y
        float p2l = __shfl_up(p2c, 1), p2r = __shfl_down(p2c, 1);
        if (eL) p2l = p2h_c;
        if (eR) p2r = p2h_c;

        // assemble outputs for row y
        float t12  = (p1p - p1m + p2r - p2l) * K1c;
        float lapp = (plc + prc + pc_m1 + pc_p1 - 4.0f * pc_0) * INVD2;
        float lapt = (tlc + trc + tm + tn - 4.0f * tc) * INVD2;
        float mval = A_PI * atan_fast(GAMMAc * (TEQc - tc));
        float dphi = DT_TAU * (t12 + e2c * lapp
                       + pc_0 * (1.0f - pc_0) * (pc_0 - 0.5f + mval));
        // NONTEMPORAL stores: bypass L2/L3 allocation so output lines do not
        // evict the (L3-fitting) input arrays. Only change vs r12.
        __builtin_nontemporal_store(pc_0 + dphi, out_phi + gout);
        __builtin_nontemporal_store(
            fmaf(KAPPAc, dphi, fmaf(DTc, lapt, tc)), out_tempr + gout);

        // roll windows
        pc_m1 = pc_0; pc_0 = pc_p1; pc_p1 = pc_p2; pc_p2 = ph_new;
        plc = pl1; prc = pr1;
        p1m = p1c; p1c = p1p;
        p2c = p2n; e2c = e2n; p2h_c = p2h_n;
        tm = tc; tc = tn; tn = t_new;
        tlc = tl_n; trc = tr_n;
        Hm = Hc; Hc = Hp; Hp = H_new;

        oP  = (oP  + Wd) & omask;
        oT  = (oT  + Wd) & omask;
        oTH = (oTH + Wd) & omask;
        gout += Wd;
    }
}

extern "C" void kernel_launch(void* const* d_in, const int* in_sizes, int n_in,
                              void* d_out, int out_size, void* d_ws, size_t ws_size,
                              hipStream_t stream) {
    const float* phi = (const float*)d_in[0];
    const float* tempr = (const float*)d_in[1];
    float* out_phi = (float*)d_out;
    float* out_tempr = out_phi + (size_t)Bz * Hd * Wd;

    dim3 grid(Wd / 64, Hd / (WPB * SH), Bz);
    dendrite_step<<<grid, 256, 0, stream>>>(phi, tempr, out_phi, out_tempr);
}